// Round 6
// baseline (595.415 us; speedup 1.0000x reference)
//
#include <hip/hip_runtime.h>
#include <math.h>

// ============================================================================
// acsasrec_decode2 v5.
//  - Dual-B GEMM core: one A-stage, two B-tiles, two accumulators
//    (32 MFMA per staged A-tile; A HBM traffic halved vs v4).
//    Pairs: {q,k}(A=xb), {p,m}(A=bb), {v n,n+256}(A=vb), {posq,posk},
//    FFN1/FFN2/d-gemm pair adjacent n-tiles.
//  - Balanced attention: block (qh,h,b) owns strips {qh, 3-qh}
//    (rows {0-127,384-511} / {128-255,256-383}); qh=1 needs only 6 k-tiles.
//  - 10 dispatches.
// ============================================================================

typedef unsigned short u16;
typedef __attribute__((ext_vector_type(8))) short bf16x8;
typedef __attribute__((ext_vector_type(4))) float f32x4;

#define NM 16384        // B*S tokens

__device__ __forceinline__ u16 f2b(float f) {
  union { float f; unsigned u; } x; x.f = f;
  return (u16)((x.u + 0x7fffu + ((x.u >> 16) & 1u)) >> 16);  // RNE
}
__device__ __forceinline__ float b2f(u16 u) {
  union { unsigned u; float f; } x; x.u = ((unsigned)u) << 16; return x.f;
}
__device__ __forceinline__ f32x4 mfma16(bf16x8 a, bf16x8 b, f32x4 c) {
  return __builtin_amdgcn_mfma_f32_16x16x32_bf16(a, b, c, 0, 0, 0);
}
// async global->LDS, 16B/lane; LDS dest = wave-uniform base + lane*16.
__device__ __forceinline__ void gl16(const u16* g, u16* l) {
  __builtin_amdgcn_global_load_lds(
      (const __attribute__((address_space(1))) unsigned int*)(const void*)g,
      (__attribute__((address_space(3))) unsigned int*)(void*)l, 16, 0, 0);
}
__device__ __forceinline__ bf16x8 baddv(bf16x8 a, bf16x8 b) {
  bf16x8 r;
  #pragma unroll
  for (int e = 0; e < 8; ++e) r[e] = (short)f2b(b2f((u16)a[e]) + b2f((u16)b[e]));
  return r;
}

// ---------------- dual-B BK=32 K-loop ----------------
// One A tile (rows m0..m0+127) staged per iter feeds two B tiles
// (W1 rows n0a.., W2 rows n0b..). If vres: add staged-A element (value
// residual) into acc when the k-window covers the output column range.
__device__ __forceinline__ void kloop2(
    const u16* __restrict__ A, const u16* __restrict__ W1,
    const u16* __restrict__ W2, int m0, int n0a, int n0b, int K, int kiters,
    u16* As, u16* B1, u16* B2, bool vres,
    f32x4 (&acc1)[4][4], f32x4 (&acc2)[4][4])
{
  const int tid = threadIdx.x;
  const int wave = tid>>6, lane = tid&63, quad = lane>>4, l16 = lane&15;
  const int wm = wave>>1, wn = wave&1;
  const int r1 = tid>>2, ch1 = (tid&3)*8;
  const u16* pA  = A  + (size_t)(m0 +r1)*K + ch1;
  const u16* pB1 = W1 + (size_t)(n0a+r1)*K + ch1;
  const u16* pB2 = W2 + (size_t)(n0b+r1)*K + ch1;
  u16* sa = As + tid*8;  u16* s1 = B1 + tid*8;  u16* s2 = B2 + tid*8;
  for (int it = 0; it < kiters; ++it) {
    const int k0 = it*32;
    gl16(pA  + k0, sa); gl16(pA  + (size_t)64*K + k0, sa + 2048);
    gl16(pB1 + k0, s1); gl16(pB1 + (size_t)64*K + k0, s1 + 2048);
    gl16(pB2 + k0, s2); gl16(pB2 + (size_t)64*K + k0, s2 + 2048);
    __syncthreads();
    bf16x8 af[4], bf[4], bg[4];
    #pragma unroll
    for (int i = 0; i < 4; ++i)
      af[i] = *(const bf16x8*)&As[(wm*64 + i*16 + l16)*32 + quad*8];
    #pragma unroll
    for (int j = 0; j < 4; ++j) {
      bf[j] = *(const bf16x8*)&B1[(wn*64 + j*16 + l16)*32 + quad*8];
      bg[j] = *(const bf16x8*)&B2[(wn*64 + j*16 + l16)*32 + quad*8];
    }
    if (vres) {     // value residual from staged A-tile (N==K==512 space)
      #pragma unroll
      for (int j = 0; j < 4; ++j) {
        const int s1c = n0a + wn*64 + j*16;
        if ((s1c & ~31) == k0) {
          const int c = (s1c & 31) + l16;
          #pragma unroll
          for (int i = 0; i < 4; ++i)
            #pragma unroll
            for (int rr = 0; rr < 4; ++rr)
              acc1[i][j][rr] += b2f(As[(wm*64 + i*16 + quad*4 + rr)*32 + c]);
        }
        const int s2c = n0b + wn*64 + j*16;
        if ((s2c & ~31) == k0) {
          const int c = (s2c & 31) + l16;
          #pragma unroll
          for (int i = 0; i < 4; ++i)
            #pragma unroll
            for (int rr = 0; rr < 4; ++rr)
              acc2[i][j][rr] += b2f(As[(wm*64 + i*16 + quad*4 + rr)*32 + c]);
        }
      }
    }
    #pragma unroll
    for (int i = 0; i < 4; ++i)
      #pragma unroll
      for (int j = 0; j < 4; ++j) {
        acc1[i][j] = mfma16(af[i], bf[j], acc1[i][j]);
        acc2[i][j] = mfma16(af[i], bg[j], acc2[i][j]);
      }
    __syncthreads();
  }
}

// ---------------- standard epilogue: acc -> LDS bf16 tile -> 16B stores -----
// exmode: 0 none | 1 ex[(gr%512)*512+gc] (bf16)
__device__ __forceinline__ void epi_std(
    f32x4 (&acc)[4][4], const float* __restrict__ bias,
    const u16* __restrict__ ex, int exmode, float scale, int gelu,
    u16* __restrict__ out, int m0, int n0, int N, u16* til)
{
  const int tid = threadIdx.x;
  const int wave = tid>>6, lane = tid&63, quad = lane>>4, l16 = lane&15;
  const int wm = wave>>1, wn = wave&1;
  #pragma unroll
  for (int pass = 0; pass < 2; ++pass) {
    if (wm == pass) {
      #pragma unroll
      for (int j = 0; j < 4; ++j) {
        const int c = wn*64 + j*16 + l16;
        const float bv = bias[n0 + c];
        #pragma unroll
        for (int i = 0; i < 4; ++i)
          #pragma unroll
          for (int rr = 0; rr < 4; ++rr) {
            float v = acc[i][j][rr] + bv;
            if (gelu) v = 0.5f*v*(1.0f + erff(v*0.70710678118654752f));
            til[(i*16 + quad*4 + rr)*136 + c] = f2b(v);
          }
      }
    }
    __syncthreads();
    const int r = tid>>2, ck = tid&3;
    const int gr = m0 + pass*64 + r;
    #pragma unroll
    for (int kk = 0; kk < 4; ++kk) {
      const int cc = ck*32 + kk*8, gc = n0 + cc;
      u16 e8[8];
      *(uint4*)e8 = *(const uint4*)&til[r*136 + cc];
      if (exmode) {
        const u16* ep = &ex[(size_t)(gr & 511)*512 + gc];
        #pragma unroll
        for (int e = 0; e < 8; ++e) e8[e] = f2b((b2f(e8[e]) + b2f(ep[e]))*scale);
      } else if (scale != 1.0f) {
        #pragma unroll
        for (int e = 0; e < 8; ++e) e8[e] = f2b(b2f(e8[e])*scale);
      }
      *(uint4*)&out[(size_t)gr*N + gc] = *(uint4*)e8;
    }
    __syncthreads();
  }
}

// ---------------- V epilogue: transposed store -> Vt[B*8*64, 512] ----------
__device__ __forceinline__ void epi_vt(
    f32x4 (&acc)[4][4], const float* __restrict__ bias,
    u16* __restrict__ Vt, int m0, int n0, u16* til)
{
  const int tid = threadIdx.x;
  const int wave = tid>>6, lane = tid&63, quad = lane>>4, l16 = lane&15;
  const int wm = wave>>1, wn = wave&1;
  const int b = m0 >> 9, s0 = m0 & 511;
  #pragma unroll
  for (int pass = 0; pass < 2; ++pass) {
    if (wn == pass) {
      #pragma unroll
      for (int j = 0; j < 4; ++j) {
        const int cl = j*16 + l16;                 // 0..63
        const float bv = bias[n0 + pass*64 + cl];
        #pragma unroll
        for (int i = 0; i < 4; ++i)
          #pragma unroll
          for (int rr = 0; rr < 4; ++rr)
            til[cl*136 + wm*64 + i*16 + quad*4 + rr] = f2b(acc[i][j][rr] + bv);
      }
    }
    __syncthreads();
    const int cl = tid>>2, ck = tid&3;
    const int gn = n0 + pass*64 + cl, h = gn>>6, d = gn&63;
    u16* orow = Vt + ((size_t)((b*8 + h)*64 + d))*512 + s0 + ck*32;
    #pragma unroll
    for (int kk = 0; kk < 4; ++kk)
      *(uint4*)&orow[kk*8] = *(const uint4*)&til[cl*136 + ck*32 + kk*8];
    __syncthreads();
  }
}

// ---------------- projection kernel (dual-B pairs, N=K=512) ----------------
// pairs: 0 {q,k}(A=xb) 1 {p,m}(A=bb) 2 {v n,n+256}(A=vb) 3 {posq,posk}
struct PJ2 { const u16* A; const u16* W1; const u16* W2;
             const float* b1; const float* b2;
             const u16* ex1; const u16* ex2;
             u16* o1; u16* o2; float sc1; float sc2;
             int ex1m; int ex2m; int dn; int epiv; };
struct ProjArgs { PJ2 p[4]; };

__global__ __launch_bounds__(256, 2) void proj_kernel(ProjArgs pa, int mode) {
  __shared__ __align__(16) u16 smem[12288];  // As | B1 | B2 ; til aliases
  u16* As = smem;  u16* B1 = smem + 4096;  u16* B2 = smem + 8192;
  int pi, nidx;
  if (mode) { pi = 3; nidx = blockIdx.x; }
  else if (blockIdx.x < 4)  { pi = 0; nidx = blockIdx.x; }
  else if (blockIdx.x < 8)  { pi = 1; nidx = blockIdx.x - 4; }
  else                      { pi = 2; nidx = blockIdx.x - 8; }
  const PJ2 P = pa.p[pi];
  const int n0a = nidx*128, n0b = n0a + P.dn;
  const int m0 = blockIdx.y*128;
  f32x4 acc1[4][4] = {};  f32x4 acc2[4][4] = {};
  kloop2(P.A, P.W1, P.W2, m0, n0a, n0b, 512, 16, As, B1, B2, P.epiv != 0,
         acc1, acc2);
  if (P.epiv) {
    epi_vt(acc1, P.b1, P.o1, m0, n0a, smem);
    epi_vt(acc2, P.b2, P.o2, m0, n0b, smem);
  } else {
    epi_std(acc1, P.b1, P.ex1, P.ex1m, P.sc1, 0, P.o1, m0, n0a, 512, smem);
    epi_std(acc2, P.b2, P.ex2, P.ex2m, P.sc2, 0, P.o2, m0, n0b, 512, smem);
  }
}

// ---------------- dual-N single GEMM (d-proj, FFN1, FFN2) ----------------
template<int GELU>
__global__ __launch_bounds__(256, 2) void gemm2_kernel(
    const u16* __restrict__ A, const u16* __restrict__ W,
    const float* __restrict__ bias, u16* __restrict__ out, int N, int K)
{
  __shared__ __align__(16) u16 smem[12288];
  const int m0 = blockIdx.y*128;
  const int n0a = blockIdx.x*256, n0b = n0a + 128;
  f32x4 acc1[4][4] = {};  f32x4 acc2[4][4] = {};
  kloop2(A, W, W, m0, n0a, n0b, K, K>>5, smem, smem + 4096, smem + 8192,
         false, acc1, acc2);
  epi_std(acc1, bias, nullptr, 0, 1.0f, GELU, out, m0, n0a, N, smem);
  epi_std(acc2, bias, nullptr, 0, 1.0f, GELU, out, m0, n0b, N, smem);
}

// ---------------- cast f32 -> bf16 (all inputs) ----------------
__global__ __launch_bounds__(256) void cast_all_kernel(
    const float* __restrict__ x, const float* __restrict__ v,
    const float* __restrict__ be, const float* __restrict__ pos,
    u16* __restrict__ xb, u16* __restrict__ vb, u16* __restrict__ bb,
    u16* __restrict__ posb)
{
  int z = blockIdx.y;
  const float* in = (z==0) ? x : (z==1) ? v : (z==2) ? be : pos;
  u16* out = (z==0) ? xb : (z==1) ? vb : (z==2) ? bb : posb;
  int n4 = (z < 3) ? (NM*512/4) : (512*512/4);
  int i = blockIdx.x*256 + threadIdx.x;
  if (i >= n4) return;
  float4 w = ((const float4*)in)[i];
  ((ushort4*)out)[i] = make_ushort4(f2b(w.x), f2b(w.y), f2b(w.z), f2b(w.w));
}

// ---------------- weight prep: transpose+cast 10 weights + biases ----------
struct PrepArgs {
  const float* w[10];  // Wq Wk Wv Wpk Wpq Wbk Wbq Wd W1 W2
  u16* o[10];
  const float* bbq; const float* bbk;
  float* Bq2; float* Bk2;
};
__global__ __launch_bounds__(256) void wprep_all_kernel(PrepArgs a) {
  int job = blockIdx.x;
  if (job == 1024) {   // Bq2 = 0.5*bbq ; Bk2 = 0.5*bbk
    for (int i = threadIdx.x; i < 512; i += 256) {
      a.Bq2[i] = 0.5f*a.bbq[i];
      a.Bk2[i] = 0.5f*a.bbk[i];
    }
    return;
  }
  int wsel, n0, k0, K, N;
  if (job < 512)      { wsel = job>>6; int t = job&63;  n0=(t&7)*64;  k0=(t>>3)*64; K=512;  N=512; }
  else if (job < 768) { wsel = 8;      int t = job-512; n0=(t&31)*64; k0=(t>>5)*64; K=512;  N=2048; }
  else                { wsel = 9;      int t = job-768; n0=(t&7)*64;  k0=(t>>3)*64; K=2048; N=512; }
  float sc = (wsel == 5 || wsel == 6) ? 0.5f : 1.0f;    // Wbk, Wbq pre-scaled
  const float* in = a.w[wsel];
  u16* out = a.o[wsel];
  __shared__ __align__(16) u16 til[64*72];
  for (int idx = threadIdx.x; idx < 4096; idx += 256) {
    int r = idx>>6, c = idx&63;
    til[r*72+c] = f2b(in[(size_t)(k0+r)*N + n0+c] * sc);
  }
  __syncthreads();
  for (int idx = threadIdx.x; idx < 4096; idx += 256) {
    int r = idx>>6, c = idx&63;
    out[(size_t)(n0+r)*K + k0+c] = til[c*72+r];
  }
}

// ---------------- flash attention v5 (balanced strip pairs) ----------------
// grid (qh=2, h=8, b=32); 512 threads; block owns strips {qh, 3-qh}
// (rows {0-127,384-511} / {128-255,256-383}); qh=1 needs only 6 k-tiles.
// Q-frags [q+p | q] combined in-register (pre-scaled /8); K-LDS = [k | m].
// No-max softmax: masked weight = exp(s)*1e-30.
__global__ __launch_bounds__(512, 2) void attn_kernel(
    const u16* __restrict__ Qraw, const u16* __restrict__ Praw,
    const u16* __restrict__ Kraw, const u16* __restrict__ Mraw,
    const u16* __restrict__ Vt, const int* __restrict__ iseq,
    u16* __restrict__ ctx)
{
  const int qh = blockIdx.x, h = blockIdx.y, b = blockIdx.z;
  const int tid = threadIdx.x;
  const int wave = tid>>6, lane = tid&63, quad = lane>>4, l16 = lane&15;

  __shared__ __align__(16) u16 Ks[2][64*136];
  __shared__ __align__(16) u16 Vs[2][64*72];
  __shared__ __align__(16) u16 Ps[8][16*72];
  __shared__ float sel[512];

  const int sbase[2] = { qh*128, (3 - qh)*128 };
  const int ntiles = qh ? 6 : 8;
  const u16* Kg = Kraw + (size_t)(b*512)*512 + h*64;
  const u16* Mg = Mraw + (size_t)(b*512)*512 + h*64;
  const u16* Vg = Vt + (size_t)((b*8 + h)*64)*512;

  if (tid < 512) sel[tid] = (iseq[b*512 + tid] > 0) ? 1.0f : 1e-30f;

  bf16x8 aq[2][4];
  #pragma unroll
  for (int s = 0; s < 2; ++s) {
    const size_t ro = (size_t)(b*512 + sbase[s] + wave*16 + l16)*512 + h*64;
    bf16x8 qf0 = *(const bf16x8*)&Qraw[ro + quad*8];
    bf16x8 qf1 = *(const bf16x8*)&Qraw[ro + 32 + quad*8];
    bf16x8 pf0 = *(const bf16x8*)&Praw[ro + quad*8];
    bf16x8 pf1 = *(const bf16x8*)&Praw[ro + 32 + quad*8];
    aq[s][0] = baddv(qf0, pf0); aq[s][1] = baddv(qf1, pf1);
    aq[s][2] = qf0;             aq[s][3] = qf1;
  }

  const int sr = tid>>3, sc8 = (tid&7)*8;
  uint4 kreg = *(const uint4*)&Kg[(size_t)sr*512 + sc8];
  uint4 mreg = *(const uint4*)&Mg[(size_t)sr*512 + sc8];
  uint4 vreg = *(const uint4*)&Vg[(size_t)sr*512 + sc8];

  f32x4 Ob[2][4] = {};
  float lrow[2][4] = {};
  u16* Pw = Ps[wave];
  int buf = 0;

  for (int kt = 0; kt < ntiles; ++kt) {
    const int k0 = kt*64;
    *(uint4*)&Ks[buf][sr*136 + sc8]      = kreg;
    *(uint4*)&Ks[buf][sr*136 + 64 + sc8] = mreg;
    *(uint4*)&Vs[buf][sr*72 + sc8]       = vreg;
    __syncthreads();
    if (kt + 1 < ntiles) {
      const int kn = k0 + 64;
      kreg = *(const uint4*)&Kg[(size_t)(kn + sr)*512 + sc8];
      mreg = *(const uint4*)&Mg[(size_t)(kn + sr)*512 + sc8];
      vreg = *(const uint4*)&Vg[(size_t)sr*512 + kn + sc8];
    }
    const bool act0 = (sbase[0] + wave*16 + 15) >= k0;
    const bool act1 = (sbase[1] + wave*16 + 15) >= k0;   // superset (sbase[1]>sbase[0])
    if (act1) {
      f32x4 sc[2][4] = {};
      #pragma unroll
      for (int ks = 0; ks < 4; ++ks) {
        bf16x8 bk[4];
        #pragma unroll
        for (int j = 0; j < 4; ++j)
          bk[j] = *(const bf16x8*)&Ks[buf][(j*16 + l16)*136 + ks*32 + quad*8];
        if (act0) {
          #pragma unroll
          for (int j = 0; j < 4; ++j) sc[0][j] = mfma16(aq[0][ks], bk[j], sc[0][j]);
        }
        #pragma unroll
        for (int j = 0; j < 4; ++j) sc[1][j] = mfma16(aq[1][ks], bk[j], sc[1][j]);
      }
      #pragma unroll
      for (int s = 0; s < 2; ++s) {
        if (s == 0 && !act0) continue;
        const int rb = sbase[s] + wave*16 + quad*4;
        float pj[4][4];
        #pragma unroll
        for (int j = 0; j < 4; ++j) {
          int col = k0 + j*16 + l16;
          float fs = sel[col];
          #pragma unroll
          for (int r = 0; r < 4; ++r) {
            float m2 = (col <= rb + r) ? fs : 1e-30f;
            pj[j][r] = __expf(sc[s][j][r]) * m2;
          }
        }
        #pragma unroll
        for (int r = 0; r < 4; ++r)
          lrow[s][r] += pj[0][r] + pj[1][r] + pj[2][r] + pj[3][r];
        #pragma unroll
        for (int j = 0; j < 4; ++j)
          #pragma unroll
          for (int r = 0; r < 4; ++r)
            Pw[(quad*4 + r)*72 + j*16 + l16] = f2b(pj[j][r]);
        #pragma unroll
        for (int c = 0; c < 4; ++c) {
          #pragma unroll
          for (int k2 = 0; k2 < 2; ++k2) {
            bf16x8 ap = *(const bf16x8*)&Pw[l16*72 + k2*32 + quad*8];
            bf16x8 bv = *(const bf16x8*)&Vs[buf][(c*16 + l16)*72 + k2*32 + quad*8];
            Ob[s][c] = mfma16(ap, bv, Ob[s][c]);
          }
        }
      }
    }
    buf ^= 1;
  }

  #pragma unroll
  for (int s = 0; s < 2; ++s) {
    #pragma unroll
    for (int r = 0; r < 4; ++r) {
      float l = lrow[s][r];
      #pragma unroll
      for (int d2 = 1; d2 < 16; d2 <<= 1) l += __shfl_xor(l, d2, 64);
      float inv = 1.0f / l;
      int grow = b*512 + sbase[s] + wave*16 + quad*4 + r;
      #pragma unroll
      for (int c = 0; c < 4; ++c)
        ctx[(size_t)grow*512 + h*64 + c*16 + l16] = f2b(Ob[s][c][r]*inv);
    }
  }
}

// ---------------- LayerNorm over H=512 (bf16 main input) ----------------
// RES: 0 = f32 residual, 1 = bf16 residual.
template<int RES>
__global__ __launch_bounds__(256) void ln_kernel(
    const u16* __restrict__ a, const void* __restrict__ resv,
    const float* __restrict__ g, const float* __restrict__ be,
    float* __restrict__ of, u16* __restrict__ ob)
{
  const int wave = threadIdx.x >> 6, lane = threadIdx.x & 63;
  const int row = blockIdx.x*4 + wave;
  const ushort4* pa = (const ushort4*)(a + (size_t)row*512);
  ushort4 a0 = pa[lane], a1 = pa[lane+64];
  float v[8] = { b2f(a0.x), b2f(a0.y), b2f(a0.z), b2f(a0.w),
                 b2f(a1.x), b2f(a1.y), b2f(a1.z), b2f(a1.w) };
  if (RES == 1) {
    const ushort4* pr = (const ushort4*)((const u16*)resv + (size_t)row*512);
    ushort4 u0 = pr[lane], u1 = pr[lane+64];
    v[0]+=b2f(u0.x); v[1]+=b2f(u0.y); v[2]+=b2f(u0.z); v[3]+=b2f(u0.w);
    v[4]+=b2f(u1.x); v[5]+=b2f(u1.y); v[6]+=b2f(u1.z); v[7]+=b2f(u1.w);
  } else {
    const float4* pr = (const float4*)((const float*)resv + (size_t)row*512);
    float4 r0 = pr[lane], r1 = pr[lane+64];
    v[0]+=r0.x; v[1]+=r0.y; v[2]+=r0.z; v[3]+=r0.w;
    v[4]+=r1.x; v[5]+=r1.y; v[6]+=r1.z; v[7]+=r1.w;
  }
  float s = 0.f, q = 0.f;
  #pragma unroll
  for (int e = 0; e < 8; ++e) { s += v[e]; q += v[e]*v[e]; }
  #pragma unroll
  for (int d = 1; d < 64; d <<= 1) { s += __shfl_xor(s, d, 64); q += __shfl_xor(q, d, 64); }
  float mean = s * (1.0f/512.0f);
  float var  = q * (1.0f/512.0f) - mean*mean;
  float rstd = rsqrtf(var + 1e-12f);
  float4 g0 = ((const float4*)g)[lane],  g1 = ((const float4*)g)[lane+64];
  float4 b0 = ((const float4*)be)[lane], b1 = ((const float4*)be)[lane+64];
  float o[8];
  o[0]=(v[0]-mean)*rstd*g0.x+b0.x; o[1]=(v[1]-mean)*rstd*g0.y+b0.y;
  o[2]=(v[2]-mean)*rstd*g0.z+b0.z; o[3]=(v[3]-mean)*rstd*g0.w+b0.w;
  o[4]=(v[4]-mean)*rstd*g1.x+b1.x; o[5]=(v[5]-mean)*rstd*g1.y+b1.y;
  o[6]=(v[6]-mean)*rstd*g1.z+b1.z; o[7]=(v[7]-mean)*rstd*g1.w+b1.w;
  if (of) {
    ((float4*)(of + (size_t)row*512))[lane]    = make_float4(o[0],o[1],o[2],o[3]);
    ((float4*)(of + (size_t)row*512))[lane+64] = make_float4(o[4],o[5],o[6],o[7]);
  }
  if (ob) {
    ((ushort4*)(ob + (size_t)row*512))[lane]    = make_ushort4(f2b(o[0]),f2b(o[1]),f2b(o[2]),f2b(o[3]));
    ((ushort4*)(ob + (size_t)row*512))[lane+64] = make_ushort4(f2b(o[4]),f2b(o[5]),f2b(o[6]),f2b(o[7]));
  }
}

// ============================================================================
extern "C" void kernel_launch(void* const* d_in, const int* in_sizes, int n_in,
                              void* d_out, int out_size, void* d_ws, size_t ws_size,
                              hipStream_t stream) {
  (void)in_sizes; (void)n_in; (void)out_size; (void)ws_size;
  const float* x    = (const float*)d_in[0];
  const float* vin  = (const float*)d_in[1];
  const float* beh  = (const float*)d_in[2];
  const float* pos  = (const float*)d_in[3];
  const float* bq   = (const float*)d_in[5];
  const float* bk   = (const float*)d_in[7];
  const float* bv   = (const float*)d_in[9];
  const float* bpk  = (const float*)d_in[11];
  const float* bpq  = (const float*)d_in[13];
  const float* bbk  = (const float*)d_in[15];
  const float* bbq  = (const float*)d_in[17];
  const float* bd   = (const float*)d_in[19];
  const float* ln_g = (const float*)d_in[20];
  const float* ln_b = (const float*)d_in[21];
  const float* b1   = (const float*)d_in[23];
  const float* b2   = (const float*)d_in[25];
  const float* ln2_g= (const float*)d_in[26];
  const float* ln2_b= (const float*)d_in[27];
  const int*   iseq = (const int*)d_in[28];
  float* out = (float*)d_out;
  char* ws = (char*)d_ws;

  // ---- workspace (~145 MB) ----
  size_t off = 0;
  auto nxt = [&](size_t sz) { size_t r = off; off += (sz + 255) & ~(size_t)255; return r; };
  size_t oWT[8]; for (int i = 0; i < 8; ++i) oWT[i] = nxt(512*512*2);
  size_t oW1T = nxt((size_t)512*2048*2);
  size_t oW2T = nxt((size_t)512*2048*2);
  size_t oBq2 = nxt(512*4);
  size_t oBk2 = nxt(512*4);
  size_t oPb  = nxt(512*512*2);
  size_t oPQ  = nxt(512*512*2);           // PQs bf16
  size_t oPK  = nxt(512*512*2);           // PKs bf16
  size_t oXb  = nxt((size_t)NM*512*2);    // xb; dead after proj, reused as ab
  size_t oVb  = nxt((size_t)NM*512*2);    // vb; dead after proj, reused as Cb
  size_t oBb  = nxt((size_t)NM*512*2);    // bb
  size_t oQr  = nxt((size_t)NM*512*2);    // Qraw (Qr..Mr contiguous; h1b after attn)
  size_t oPr  = nxt((size_t)NM*512*2);    // Praw
  size_t oKr  = nxt((size_t)NM*512*2);    // Kraw
  size_t oMr  = nxt((size_t)NM*512*2);    // Mraw
  size_t oVt  = nxt((size_t)NM*512*2);    // Vt; dead after attn, reused as f2

  u16* WT[8]; for (int i = 0; i < 8; ++i) WT[i] = (u16*)(ws + oWT[i]);
  u16*   W1T  = (u16*)(ws + oW1T);
  u16*   W2T  = (u16*)(ws + oW2T);
  float* Bq2  = (float*)(ws + oBq2);
  float* Bk2  = (float*)(ws + oBk2);
  u16*   posb = (u16*)(ws + oPb);
  u16*   PQs  = (u16*)(ws + oPQ);
  u16*   PKs  = (u16*)(ws + oPK);
  u16*   xb   = (u16*)(ws + oXb);
  u16*   vb   = (u16*)(ws + oVb);
  u16*   bb   = (u16*)(ws + oBb);
  u16*   Qraw = (u16*)(ws + oQr);
  u16*   Praw = (u16*)(ws + oPr);
  u16*   Kraw = (u16*)(ws + oKr);
  u16*   Mraw = (u16*)(ws + oMr);
  u16*   Vtb  = (u16*)(ws + oVt);
  u16*   Cb   = (u16*)(ws + oVb);   // alias: vb dead after proj
  u16*   db   = (u16*)(ws + oPr);   // alias: Praw dead after attn (LN1 reads before FFN1 writes h1b)
  u16*   ab   = (u16*)(ws + oXb);   // alias: xb dead after proj
  u16*   h1b  = (u16*)(ws + oQr);   // alias: Qraw..Mraw dead after attn (67 MB)
  u16*   f2   = (u16*)(ws + oVt);   // alias: Vt dead after attn

  // 1. casts
  cast_all_kernel<<<dim3(8192, 4), 256, 0, stream>>>(x, vin, beh, pos, xb, vb, bb, posb);
  // 2. weight prep + combined biases
  PrepArgs pr;
  const int wi[10] = {4, 6, 8, 10, 12, 14, 16, 18, 22, 24};
  for (int i = 0; i < 10; ++i) pr.w[i] = (const float*)d_in[wi[i]];
  for (int i = 0; i < 8; ++i)  pr.o[i] = WT[i];
  pr.o[8] = W1T; pr.o[9] = W2T;
  pr.bbq = bbq; pr.bbk = bbk; pr.Bq2 = Bq2; pr.Bk2 = Bk2;
  wprep_all_kernel<<<1025, 256, 0, stream>>>(pr);
  // dual-B pair table
  ProjArgs pj;
  pj.p[0] = { xb,   WT[0], WT[1], bq,  bk,  nullptr, nullptr, Qraw, Kraw,
              0.125f, 1.0f, 0, 0, 0,   0 };
  pj.p[1] = { bb,   WT[6], WT[5], Bq2, Bk2, PQs,     PKs,     Praw, Mraw,
              0.125f, 1.0f, 1, 1, 0,   0 };
  pj.p[2] = { vb,   WT[2], WT[2], bv,  bv,  nullptr, nullptr, Vtb,  Vtb,
              1.0f,   1.0f, 0, 0, 256, 1 };
  pj.p[3] = { posb, WT[4], WT[3], bpq, bpk, nullptr, nullptr, PQs,  PKs,
              0.5f,   0.5f, 0, 0, 0,   0 };
  // 3. position projections (pair 3)
  proj_kernel<<<dim3(4, 4), 256, 0, stream>>>(pj, 1);
  // 4. q,k,p,m,v projections (pairs 0..2)
  proj_kernel<<<dim3(10, 128), 256, 0, stream>>>(pj, 0);
  // 5. attention
  attn_kernel<<<dim3(2, 8, 32), 512, 0, stream>>>(Qraw, Praw, Kraw, Mraw, Vtb, iseq, Cb);
  // 6. output projection -> bf16
  gemm2_kernel<0><<<dim3(2, 128), 256, 0, stream>>>(Cb, WT[7], bd, db, 512, 512);
  // 7. LN1 (+ f32 x residual) -> bf16
  ln_kernel<0><<<4096, 256, 0, stream>>>(db, x, ln_g, ln_b, nullptr, ab);
  // 8. FFN1 (gelu) -> bf16
  gemm2_kernel<1><<<dim3(8, 128), 256, 0, stream>>>(ab, W1T, b1, h1b, 2048, 512);
  // 9. FFN2 -> bf16
  gemm2_kernel<0><<<dim3(2, 128), 256, 0, stream>>>(h1b, W2T, b2, f2, 512, 2048);
  // 10. LN2 (+ bf16 attn_out residual) -> f32 out
  ln_kernel<1><<<4096, 256, 0, stream>>>(f2, ab, ln2_g, ln2_b, out, nullptr);
}